// Round 2
// baseline (395.330 us; speedup 1.0000x reference)
//
#include <hip/hip_runtime.h>
#include <hip/hip_bf16.h>
#include <math.h>

#define BB 16
#define NN 8192
#define DD 768
#define HH 3072
#define EPSV 1e-6f
#define DSQRT 0.03608439182435161f   // 768^-0.5

#define CHUNKS 64
#define ROWS_PER_BLOCK (NN / CHUNKS)              // 128
#define NWAVES 4
#define ROWS_PER_WAVE (ROWS_PER_BLOCK / NWAVES)   // 32
#define RB 4                                      // rows batched per iteration
#define PSTRIDE 772                               // 768 pooled + 1 denom (x4 pad)

// ---------------------------------------------------------------------------
// Kernel A: single pass over x. 4 rows per iteration: 12 float4 loads in
// flight, 4 interleaved shuffle-reduce chains, float4 logit store.
// No max-subtraction needed: |logit*DSQRT| <~ 0.2 for N(0,1) inputs.
// ---------------------------------------------------------------------------
__global__ __launch_bounds__(256) void attn_pool_k(
    const float* __restrict__ x, const float* __restrict__ query,
    float* __restrict__ attn_out, float* __restrict__ partials)
{
    const int b     = blockIdx.y;
    const int chunk = blockIdx.x;
    const int tid   = threadIdx.x;
    const int wave  = tid >> 6;
    const int lane  = tid & 63;

    const float4* q4 = (const float4*)query;
    const float4 q0 = q4[lane];
    const float4 q1 = q4[lane + 64];
    const float4 q2 = q4[lane + 128];

    float4 p0 = make_float4(0.f, 0.f, 0.f, 0.f);
    float4 p1 = make_float4(0.f, 0.f, 0.f, 0.f);
    float4 p2 = make_float4(0.f, 0.f, 0.f, 0.f);
    float esum = 0.f;

    const int n0 = chunk * ROWS_PER_BLOCK + wave * ROWS_PER_WAVE;
    const float4* xb = (const float4*)(x + (size_t)b * NN * DD);

    for (int it = 0; it < ROWS_PER_WAVE / RB; ++it) {
        const int n = n0 + it * RB;
        float4 v[RB][3];
        #pragma unroll
        for (int r = 0; r < RB; ++r) {
            const float4* xr = xb + (size_t)(n + r) * (DD / 4);
            v[r][0] = xr[lane];
            v[r][1] = xr[lane + 64];
            v[r][2] = xr[lane + 128];
        }

        float s[RB];
        #pragma unroll
        for (int r = 0; r < RB; ++r) {
            float a;
            a  = v[r][0].x * q0.x + v[r][0].y * q0.y + v[r][0].z * q0.z + v[r][0].w * q0.w;
            a += v[r][1].x * q1.x + v[r][1].y * q1.y + v[r][1].z * q1.z + v[r][1].w * q1.w;
            a += v[r][2].x * q2.x + v[r][2].y * q2.y + v[r][2].z * q2.z + v[r][2].w * q2.w;
            s[r] = a;
        }

        // 4 interleaved butterfly reduces (latency amortized across rows)
        #pragma unroll
        for (int k = 0; k < 6; ++k) {
            const int off = 32 >> k;
            #pragma unroll
            for (int r = 0; r < RB; ++r) s[r] += __shfl_xor(s[r], off);
        }

        if (lane == 0)
            *(float4*)&attn_out[(size_t)b * NN + n] = make_float4(s[0], s[1], s[2], s[3]);

        float e[RB];
        #pragma unroll
        for (int r = 0; r < RB; ++r) { e[r] = expf(s[r] * DSQRT); esum += e[r]; }

        #pragma unroll
        for (int r = 0; r < RB; ++r) {
            p0.x += e[r] * v[r][0].x; p0.y += e[r] * v[r][0].y;
            p0.z += e[r] * v[r][0].z; p0.w += e[r] * v[r][0].w;
            p1.x += e[r] * v[r][1].x; p1.y += e[r] * v[r][1].y;
            p1.z += e[r] * v[r][1].z; p1.w += e[r] * v[r][1].w;
            p2.x += e[r] * v[r][2].x; p2.y += e[r] * v[r][2].y;
            p2.z += e[r] * v[r][2].z; p2.w += e[r] * v[r][2].w;
        }
    }

    __shared__ float lds[NWAVES][PSTRIDE];
    float* my = lds[wave];
    *(float4*)&my[lane * 4]       = p0;
    *(float4*)&my[256 + lane * 4] = p1;
    *(float4*)&my[512 + lane * 4] = p2;
    if (lane == 0) my[768] = esum;
    __syncthreads();

    float* outp = partials + (size_t)(b * CHUNKS + chunk) * PSTRIDE;
    #pragma unroll
    for (int k = 0; k < 3; ++k) {
        const int idx = tid + k * 256;
        outp[idx] = lds[0][idx] + lds[1][idx] + lds[2][idx] + lds[3][idx];
    }
    if (tid == 0) outp[768] = lds[0][768] + lds[1][768] + lds[2][768] + lds[3][768];
}

// ---------------------------------------------------------------------------
// Kernel B: per-batch reduce of chunk partials -> pooled, then LayerNorm.
// ---------------------------------------------------------------------------
__global__ __launch_bounds__(256) void reduce_ln_k(
    const float* __restrict__ partials, const float* __restrict__ gamma,
    const float* __restrict__ beta, float* __restrict__ pooled_ws,
    float* __restrict__ hln_ws)
{
    const int b = blockIdx.x, tid = threadIdx.x;
    const float* pb = partials + (size_t)b * CHUNKS * PSTRIDE;

    float v[3];
    #pragma unroll
    for (int k = 0; k < 3; ++k) {
        const int idx = tid + k * 256;
        float s = 0.f;
        #pragma unroll 4
        for (int c = 0; c < CHUNKS; ++c) s += pb[c * PSTRIDE + idx];
        v[k] = s;
    }

    __shared__ float s_den;
    if (tid < 64) {
        float dn = pb[tid * PSTRIDE + 768];
        #pragma unroll
        for (int off = 32; off > 0; off >>= 1) dn += __shfl_xor(dn, off);
        if (tid == 0) s_den = dn;
    }
    __syncthreads();
    const float inv = 1.f / s_den;
    #pragma unroll
    for (int k = 0; k < 3; ++k) v[k] *= inv;

    __shared__ float red[256];
    red[tid] = v[0] + v[1] + v[2];
    __syncthreads();
    for (int s = 128; s > 0; s >>= 1) {
        if (tid < s) red[tid] += red[tid + s];
        __syncthreads();
    }
    const float mu = red[0] * (1.f / 768.f);
    __syncthreads();

    float sq = 0.f;
    #pragma unroll
    for (int k = 0; k < 3; ++k) { const float d = v[k] - mu; sq += d * d; }
    red[tid] = sq;
    __syncthreads();
    for (int s = 128; s > 0; s >>= 1) {
        if (tid < s) red[tid] += red[tid + s];
        __syncthreads();
    }
    const float var = red[0] * (1.f / 768.f);
    const float rstd = rsqrtf(var + EPSV);

    #pragma unroll
    for (int k = 0; k < 3; ++k) {
        const int idx = tid + k * 256;
        pooled_ws[(size_t)b * DD + idx] = v[k];
        hln_ws[(size_t)b * DD + idx] = (v[k] - mu) * rstd * gamma[idx] + beta[idx];
    }
}

// ---------------------------------------------------------------------------
// Kernel C: h1 = gelu(hln @ w1 + b1), exact gelu. Thread owns 4 columns.
// ---------------------------------------------------------------------------
__global__ __launch_bounds__(256) void gemm1_gelu_k(
    const float* __restrict__ hln_ws, const float* __restrict__ w1,
    const float* __restrict__ b1, float* __restrict__ h1_ws)
{
    const int b = blockIdx.y;
    const int j4 = (blockIdx.x * 256 + threadIdx.x) * 4;

    __shared__ float hl[DD];
    for (int i = threadIdx.x; i < DD; i += 256) hl[i] = hln_ws[(size_t)b * DD + i];
    __syncthreads();

    float4 acc = *(const float4*)&b1[j4];
    #pragma unroll 4
    for (int d = 0; d < DD; ++d) {
        const float4 w = *(const float4*)&w1[(size_t)d * HH + j4];
        const float h = hl[d];
        acc.x += h * w.x; acc.y += h * w.y; acc.z += h * w.z; acc.w += h * w.w;
    }
    float4 g;
    g.x = 0.5f * acc.x * (1.f + erff(acc.x * 0.70710678118654752f));
    g.y = 0.5f * acc.y * (1.f + erff(acc.y * 0.70710678118654752f));
    g.z = 0.5f * acc.z * (1.f + erff(acc.z * 0.70710678118654752f));
    g.w = 0.5f * acc.w * (1.f + erff(acc.w * 0.70710678118654752f));
    *(float4*)&h1_ws[(size_t)b * HH + j4] = g;
}

// ---------------------------------------------------------------------------
// Kernel D: out = pooled + b2 + h1 @ w2  (fused, single dispatch,
// deterministic: full K-loop inside one block).
// ---------------------------------------------------------------------------
__global__ __launch_bounds__(256) void gemm2_fin_k(
    const float* __restrict__ h1_ws, const float* __restrict__ w2,
    const float* __restrict__ pooled_ws, const float* __restrict__ b2,
    float* __restrict__ out)
{
    const int b   = blockIdx.y;
    const int col = blockIdx.x * 256 + threadIdx.x;   // grid.x = 3 -> 768 cols

    __shared__ float hg[HH];
    for (int i = threadIdx.x; i < HH; i += 256) hg[i] = h1_ws[(size_t)b * HH + i];
    __syncthreads();

    float acc = 0.f;
    #pragma unroll 8
    for (int j = 0; j < HH; ++j) acc += hg[j] * w2[(size_t)j * DD + col];

    out[(size_t)b * DD + col] = pooled_ws[(size_t)b * DD + col] + b2[col] + acc;
}

extern "C" void kernel_launch(void* const* d_in, const int* in_sizes, int n_in,
                              void* d_out, int out_size, void* d_ws, size_t ws_size,
                              hipStream_t stream)
{
    const float* x     = (const float*)d_in[0];
    const float* query = (const float*)d_in[1];
    const float* gamma = (const float*)d_in[2];
    const float* beta  = (const float*)d_in[3];
    const float* w1    = (const float*)d_in[4];
    const float* b1    = (const float*)d_in[5];
    const float* w2    = (const float*)d_in[6];
    const float* b2    = (const float*)d_in[7];

    float* out      = (float*)d_out;       // [16][768]
    float* attn_out = out + BB * DD;       // [16][8192] raw logits

    float* ws       = (float*)d_ws;
    float* partials = ws;                               // 16*64*772
    float* pooled   = partials + BB * CHUNKS * PSTRIDE;
    float* hln      = pooled + BB * DD;
    float* h1       = hln + BB * DD;                    // 16*3072

    attn_pool_k<<<dim3(CHUNKS, BB), 256, 0, stream>>>(x, query, attn_out, partials);
    reduce_ln_k<<<dim3(BB), 256, 0, stream>>>(partials, gamma, beta, pooled, hln);
    gemm1_gelu_k<<<dim3(HH / 1024, BB), 256, 0, stream>>>(hln, w1, b1, h1);
    gemm2_fin_k<<<dim3(DD / 256, BB), 256, 0, stream>>>(h1, w2, pooled, b2, out);
}

// Round 3
// 116.308 us; speedup vs baseline: 3.3990x; 3.3990x over previous
//
#include <hip/hip_runtime.h>
#include <hip/hip_bf16.h>
#include <math.h>

#define BB 16
#define NN 8192
#define DD 768
#define HH 3072
#define EPSV 1e-6f
#define DSQRT 0.03608439182435161f   // 768^-0.5

#define CHUNKS 64
#define ROWS_PER_BLOCK (NN / CHUNKS)              // 128
#define NWAVES 4
#define ROWS_PER_WAVE (ROWS_PER_BLOCK / NWAVES)   // 32
#define PSTRIDE 772                               // 768 pooled + 1 denom

#define KS1 16
#define KL1 (DD / KS1)    // 48
#define KS2 48
#define KL2 (HH / KS2)    // 64

// ---------------------------------------------------------------------------
// Kernel A (round-1 proven version): single pass over x.
// ---------------------------------------------------------------------------
__global__ __launch_bounds__(256) void attn_pool_k(
    const float* __restrict__ x, const float* __restrict__ query,
    float* __restrict__ attn_out, float* __restrict__ partials)
{
    const int b     = blockIdx.y;
    const int chunk = blockIdx.x;
    const int tid   = threadIdx.x;
    const int wave  = tid >> 6;
    const int lane  = tid & 63;

    const float4* q4 = (const float4*)query;
    const float4 q0 = q4[lane];
    const float4 q1 = q4[lane + 64];
    const float4 q2 = q4[lane + 128];

    float4 p0 = make_float4(0.f, 0.f, 0.f, 0.f);
    float4 p1 = make_float4(0.f, 0.f, 0.f, 0.f);
    float4 p2 = make_float4(0.f, 0.f, 0.f, 0.f);
    float esum = 0.f;

    const int n0 = chunk * ROWS_PER_BLOCK + wave * ROWS_PER_WAVE;
    const float4* xb = (const float4*)(x + (size_t)b * NN * DD);

    #pragma unroll 2
    for (int r = 0; r < ROWS_PER_WAVE; ++r) {
        const int n = n0 + r;
        const float4* xr = xb + (size_t)n * (DD / 4);
        const float4 v0 = xr[lane];
        const float4 v1 = xr[lane + 64];
        const float4 v2 = xr[lane + 128];

        float s = v0.x * q0.x + v0.y * q0.y + v0.z * q0.z + v0.w * q0.w;
        s += v1.x * q1.x + v1.y * q1.y + v1.z * q1.z + v1.w * q1.w;
        s += v2.x * q2.x + v2.y * q2.y + v2.z * q2.z + v2.w * q2.w;
        #pragma unroll
        for (int off = 32; off > 0; off >>= 1) s += __shfl_xor(s, off);

        if (lane == 0) attn_out[(size_t)b * NN + n] = s;  // raw logit

        const float e = expf(s * DSQRT);
        esum += e;
        p0.x += e * v0.x; p0.y += e * v0.y; p0.z += e * v0.z; p0.w += e * v0.w;
        p1.x += e * v1.x; p1.y += e * v1.y; p1.z += e * v1.z; p1.w += e * v1.w;
        p2.x += e * v2.x; p2.y += e * v2.y; p2.z += e * v2.z; p2.w += e * v2.w;
    }

    __shared__ float lds[NWAVES][PSTRIDE];
    float* my = lds[wave];
    *(float4*)&my[lane * 4]       = p0;
    *(float4*)&my[256 + lane * 4] = p1;
    *(float4*)&my[512 + lane * 4] = p2;
    if (lane == 0) my[768] = esum;
    __syncthreads();

    float* outp = partials + (size_t)(b * CHUNKS + chunk) * PSTRIDE;
    #pragma unroll
    for (int k = 0; k < 3; ++k) {
        const int idx = tid + k * 256;
        outp[idx] = lds[0][idx] + lds[1][idx] + lds[2][idx] + lds[3][idx];
    }
    if (tid == 0) outp[768] = lds[0][768] + lds[1][768] + lds[2][768] + lds[3][768];
}

// ---------------------------------------------------------------------------
// Kernel B: per-batch reduce of chunk partials -> pooled, then LayerNorm.
// ---------------------------------------------------------------------------
__global__ __launch_bounds__(256) void reduce_ln_k(
    const float* __restrict__ partials, const float* __restrict__ gamma,
    const float* __restrict__ beta, float* __restrict__ pooled_ws,
    float* __restrict__ hln_ws)
{
    const int b = blockIdx.x, tid = threadIdx.x;
    const float* pb = partials + (size_t)b * CHUNKS * PSTRIDE;

    float v[3];
    #pragma unroll
    for (int k = 0; k < 3; ++k) {
        const int idx = tid + k * 256;
        float s = 0.f;
        #pragma unroll 8
        for (int c = 0; c < CHUNKS; ++c) s += pb[c * PSTRIDE + idx];
        v[k] = s;
    }

    __shared__ float s_den;
    if (tid < 64) {
        float dn = pb[tid * PSTRIDE + 768];
        #pragma unroll
        for (int off = 32; off > 0; off >>= 1) dn += __shfl_xor(dn, off);
        if (tid == 0) s_den = dn;
    }
    __syncthreads();
    const float inv = 1.f / s_den;
    #pragma unroll
    for (int k = 0; k < 3; ++k) v[k] *= inv;

    __shared__ float red[256];
    red[tid] = v[0] + v[1] + v[2];
    __syncthreads();
    for (int s = 128; s > 0; s >>= 1) {
        if (tid < s) red[tid] += red[tid + s];
        __syncthreads();
    }
    const float mu = red[0] * (1.f / 768.f);
    __syncthreads();

    float sq = 0.f;
    #pragma unroll
    for (int k = 0; k < 3; ++k) { const float d = v[k] - mu; sq += d * d; }
    red[tid] = sq;
    __syncthreads();
    for (int s = 128; s > 0; s >>= 1) {
        if (tid < s) red[tid] += red[tid + s];
        __syncthreads();
    }
    const float var = red[0] * (1.f / 768.f);
    const float rstd = rsqrtf(var + EPSV);

    #pragma unroll
    for (int k = 0; k < 3; ++k) {
        const int idx = tid + k * 256;
        pooled_ws[(size_t)b * DD + idx] = v[k];
        hln_ws[(size_t)b * DD + idx] = (v[k] - mu) * rstd * gamma[idx] + beta[idx];
    }
}

// ---------------------------------------------------------------------------
// Kernel C: B-major K-split partial of hln @ w1. Thread owns one hidden
// column and all 16 batch rows; weight slice fully prefetched to registers.
// grid (HH/256=12, KS1=16)
// ---------------------------------------------------------------------------
__global__ __launch_bounds__(256) void gemm1_part_k(
    const float* __restrict__ hln_ws, const float* __restrict__ w1,
    float* __restrict__ g1p)
{
    const int j  = blockIdx.x * 256 + threadIdx.x;  // hidden column
    const int k0 = blockIdx.y * KL1;                // K offset

    __shared__ float hl[BB][KL1];
    for (int i = threadIdx.x; i < BB * KL1; i += 256) {
        const int b = i / KL1, d = i - b * KL1;
        hl[b][d] = hln_ws[(size_t)b * DD + k0 + d];
    }
    __syncthreads();

    float wv[KL1];
    #pragma unroll
    for (int d = 0; d < KL1; ++d) wv[d] = w1[(size_t)(k0 + d) * HH + j];

    float acc[BB];
    #pragma unroll
    for (int b = 0; b < BB; ++b) acc[b] = 0.f;

    #pragma unroll
    for (int d4 = 0; d4 < KL1 / 4; ++d4) {
        #pragma unroll
        for (int b = 0; b < BB; ++b) {
            const float4 h4 = *(const float4*)&hl[b][d4 * 4];
            acc[b] += h4.x * wv[d4 * 4] + h4.y * wv[d4 * 4 + 1]
                    + h4.z * wv[d4 * 4 + 2] + h4.w * wv[d4 * 4 + 3];
        }
    }

    float* op = g1p + (size_t)blockIdx.y * BB * HH;   // [ks][b][HH]
    #pragma unroll
    for (int b = 0; b < BB; ++b) op[(size_t)b * HH + j] = acc[b];
}

// ---------------------------------------------------------------------------
// Kernel D: combine K-split partials + bias + exact gelu -> h1. grid 48.
// ---------------------------------------------------------------------------
__global__ __launch_bounds__(256) void comb1_gelu_k(
    const float* __restrict__ g1p, const float* __restrict__ b1,
    float* __restrict__ h1_ws)
{
    const int i = blockIdx.x * 256 + threadIdx.x;   // float4 index, 12288 total
    const int j = (i * 4) % HH;

    float4 a = *(const float4*)&b1[j];
    #pragma unroll
    for (int s = 0; s < KS1; ++s) {
        const float4 p = *(const float4*)&g1p[(size_t)s * BB * HH + (size_t)i * 4];
        a.x += p.x; a.y += p.y; a.z += p.z; a.w += p.w;
    }
    float4 g;
    g.x = 0.5f * a.x * (1.f + erff(a.x * 0.70710678118654752f));
    g.y = 0.5f * a.y * (1.f + erff(a.y * 0.70710678118654752f));
    g.z = 0.5f * a.z * (1.f + erff(a.z * 0.70710678118654752f));
    g.w = 0.5f * a.w * (1.f + erff(a.w * 0.70710678118654752f));
    *(float4*)&h1_ws[(size_t)i * 4] = g;
}

// ---------------------------------------------------------------------------
// Kernel E: B-major K-split partial of h1 @ w2. grid (DD/256=3, KS2=48)
// ---------------------------------------------------------------------------
__global__ __launch_bounds__(256) void gemm2_part_k(
    const float* __restrict__ h1_ws, const float* __restrict__ w2,
    float* __restrict__ g2p)
{
    const int col = blockIdx.x * 256 + threadIdx.x;  // out column
    const int k0  = blockIdx.y * KL2;                // K offset

    __shared__ float hg[BB][KL2];
    for (int i = threadIdx.x; i < BB * KL2; i += 256) {
        const int b = i / KL2, d = i - b * KL2;
        hg[b][d] = h1_ws[(size_t)b * HH + k0 + d];
    }
    __syncthreads();

    float wv[KL2];
    #pragma unroll
    for (int d = 0; d < KL2; ++d) wv[d] = w2[(size_t)(k0 + d) * DD + col];

    float acc[BB];
    #pragma unroll
    for (int b = 0; b < BB; ++b) acc[b] = 0.f;

    #pragma unroll
    for (int d4 = 0; d4 < KL2 / 4; ++d4) {
        #pragma unroll
        for (int b = 0; b < BB; ++b) {
            const float4 h4 = *(const float4*)&hg[b][d4 * 4];
            acc[b] += h4.x * wv[d4 * 4] + h4.y * wv[d4 * 4 + 1]
                    + h4.z * wv[d4 * 4 + 2] + h4.w * wv[d4 * 4 + 3];
        }
    }

    float* op = g2p + (size_t)blockIdx.y * BB * DD;   // [ks][b][DD]
    #pragma unroll
    for (int b = 0; b < BB; ++b) op[(size_t)b * DD + col] = acc[b];
}

// ---------------------------------------------------------------------------
// Kernel F: out = pooled + b2 + sum_s g2p. grid 12 (float4 threads).
// ---------------------------------------------------------------------------
__global__ __launch_bounds__(256) void comb2_fin_k(
    const float* __restrict__ g2p, const float* __restrict__ pooled_ws,
    const float* __restrict__ b2, float* __restrict__ out)
{
    const int i = blockIdx.x * 256 + threadIdx.x;   // float4 index, 3072 total
    const int d = (i * 4) % DD;

    const float4 pl = *(const float4*)&pooled_ws[(size_t)i * 4];
    float4 a = *(const float4*)&b2[d];
    a.x += pl.x; a.y += pl.y; a.z += pl.z; a.w += pl.w;
    #pragma unroll
    for (int s = 0; s < KS2; ++s) {
        const float4 p = *(const float4*)&g2p[(size_t)s * BB * DD + (size_t)i * 4];
        a.x += p.x; a.y += p.y; a.z += p.z; a.w += p.w;
    }
    *(float4*)&out[(size_t)i * 4] = a;
}

extern "C" void kernel_launch(void* const* d_in, const int* in_sizes, int n_in,
                              void* d_out, int out_size, void* d_ws, size_t ws_size,
                              hipStream_t stream)
{
    const float* x     = (const float*)d_in[0];
    const float* query = (const float*)d_in[1];
    const float* gamma = (const float*)d_in[2];
    const float* beta  = (const float*)d_in[3];
    const float* w1    = (const float*)d_in[4];
    const float* b1    = (const float*)d_in[5];
    const float* w2    = (const float*)d_in[6];
    const float* b2    = (const float*)d_in[7];

    float* out      = (float*)d_out;       // [16][768]
    float* attn_out = out + BB * DD;       // [16][8192] raw logits

    float* ws       = (float*)d_ws;
    float* partials = ws;                               // 16*64*772
    float* pooled   = partials + BB * CHUNKS * PSTRIDE;
    float* hln      = pooled + BB * DD;
    float* h1       = hln + BB * DD;                    // 16*3072
    float* g1p      = h1 + BB * HH;                     // 16*16*3072
    float* g2p      = g1p + KS1 * BB * HH;              // 48*16*768

    attn_pool_k<<<dim3(CHUNKS, BB), 256, 0, stream>>>(x, query, attn_out, partials);
    reduce_ln_k<<<dim3(BB), 256, 0, stream>>>(partials, gamma, beta, pooled, hln);
    gemm1_part_k<<<dim3(HH / 256, KS1), 256, 0, stream>>>(hln, w1, g1p);
    comb1_gelu_k<<<dim3(BB * HH / 1024), 256, 0, stream>>>(g1p, b1, h1);
    gemm2_part_k<<<dim3(DD / 256, KS2), 256, 0, stream>>>(h1, w2, g2p);
    comb2_fin_k<<<dim3(BB * DD / 1024), 256, 0, stream>>>(g2p, pooled, b2, out);
}